// Round 3
// baseline (756.408 us; speedup 1.0000x reference)
//
#include <hip/hip_runtime.h>

#define B_ 32
#define K_ 10
#define T_ 128
#define L_ 128
#define D_ 1024
#define NT_ 32
#define S_ (K_*L_)      // 1280
#define NCH2_ 20        // S chunks of 64 for gemm
#define PVW_ (NCH2_*2)  // pval entries per test row
#define BIGF 1e30f

typedef __attribute__((ext_vector_type(8))) short short8;
typedef __attribute__((ext_vector_type(4))) float f32x4;

__device__ __forceinline__ unsigned short bf16rn(float f){
  unsigned int u = __float_as_uint(f);
  u = (u + 0x7FFFu + ((u >> 16) & 1u)) >> 16;
  return (unsigned short)u;
}
__device__ __forceinline__ float bf2f(unsigned int h){
  return __uint_as_float(h << 16);
}
__device__ __forceinline__ unsigned int pack2(unsigned short a, unsigned short b){
  return (unsigned int)a | ((unsigned int)b << 16);
}

// ---------------- K1: test_mean -> bf16 hi/lo planes ----------------
__global__ __launch_bounds__(256) void k_mean(const float* __restrict__ tr,
        unsigned short* __restrict__ tm_hi, unsigned short* __restrict__ tm_lo){
  int idx = blockIdx.x*256 + threadIdx.x;       // over B*T*(D/4)
  int d4 = idx & 255;
  int t  = (idx >> 8) & 127;
  int b  = idx >> 15;
  const float4* p = (const float4*)tr;
  float4 a = make_float4(0.f,0.f,0.f,0.f);
  #pragma unroll
  for(int k=0;k<K_;k++){
    float4 v = p[((size_t)(b*K_+k)*T_ + t)*(D_/4) + d4];
    a.x+=v.x; a.y+=v.y; a.z+=v.z; a.w+=v.w;
  }
  const float sc = 1.f/(float)K_;
  a.x*=sc; a.y*=sc; a.z*=sc; a.w*=sc;
  unsigned short hx=bf16rn(a.x), hy=bf16rn(a.y), hz=bf16rn(a.z), hw=bf16rn(a.w);
  unsigned short lx=bf16rn(a.x-bf2f(hx)), ly=bf16rn(a.y-bf2f(hy)),
                 lz=bf16rn(a.z-bf2f(hz)), lw=bf16rn(a.w-bf2f(hw));
  size_t o = (size_t)(b*T_ + t)*(D_/4) + d4;
  ((uint2*)tm_hi)[o] = make_uint2(pack2(hx,hy), pack2(hz,hw));
  ((uint2*)tm_lo)[o] = make_uint2(pack2(lx,ly), pack2(lz,lw));
}

// ---------------- K2: labels from one-hot targets ----------------
__global__ __launch_bounds__(256) void k_label(const float* __restrict__ tgt, int* __restrict__ labels){
  int r = blockIdx.x*256 + threadIdx.x;
  const float4* p = (const float4*)tgt + (size_t)r*8;
  int lbl = 0;
  #pragma unroll
  for(int j=0;j<8;j++){
    float4 v = p[j];
    if(v.x>0.5f) lbl=j*4+0;
    if(v.y>0.5f) lbl=j*4+1;
    if(v.z>0.5f) lbl=j*4+2;
    if(v.w>0.5f) lbl=j*4+3;
  }
  labels[r] = lbl;
}

// ---------------- K3: prototype partial sums, full-row coalesced ----------------
// grid B*8 (s-chunks of 160). LDS acc swizzled [j][tag][col>>2] -> conflict-free ds_add.
__global__ __launch_bounds__(256) void k_proto(const float* __restrict__ sup, const int* __restrict__ labels,
        float* __restrict__ psums, int* __restrict__ pcnt){
  __shared__ float acc[4][NT_][256];   // 128 KB
  __shared__ int lbl[160];
  __shared__ int cnt[NT_];
  int b = blockIdx.x >> 3, chunk = blockIdx.x & 7;
  int s0 = chunk*160;
  int tid = threadIdx.x;
  for(int i=tid;i<4*NT_*256;i+=256) (&acc[0][0][0])[i]=0.f;
  if(tid<NT_) cnt[tid]=0;
  if(tid<160) lbl[tid] = labels[b*S_ + s0 + tid];
  __syncthreads();
  if(tid<160) atomicAdd(&cnt[lbl[tid]], 1);
  const float4* base = (const float4*)(sup + ((size_t)b*S_ + s0)*D_) + tid;
  #pragma unroll 4
  for(int s=0;s<160;s++){
    float4 v = base[(size_t)s*(D_/4)];
    int l = lbl[s];
    atomicAdd(&acc[0][l][tid], v.x);
    atomicAdd(&acc[1][l][tid], v.y);
    atomicAdd(&acc[2][l][tid], v.z);
    atomicAdd(&acc[3][l][tid], v.w);
  }
  __syncthreads();
  float* gp = psums + (size_t)b*NT_*D_;
  for(int i=tid;i<NT_*D_;i+=256){       // i = j*8192 + n*256 + c
    int j = i >> 13, rem = i & 8191, n = rem >> 8, c = rem & 255;
    atomicAdd(&gp[n*D_ + c*4 + j], acc[j][n][c]);
  }
  if(tid<NT_) atomicAdd(&pcnt[b*NT_+tid], cnt[tid]);
}

// ---------------- K3b: proto = psums / (cnt + 1e-4) ----------------
__global__ __launch_bounds__(256) void k_preduce(const float* __restrict__ psums, const int* __restrict__ pcnt,
        float* __restrict__ proto){
  int i4 = blockIdx.x*256 + threadIdx.x;    // < B*NT*D/4
  int b = i4 >> 13, n = (i4 >> 8) & 31;
  float c = (float)pcnt[b*NT_+n] + 1e-4f;
  float4 v = ((const float4*)psums)[i4];
  float inv = 1.f/c;
  v.x*=inv; v.y*=inv; v.z*=inv; v.w*=inv;
  ((float4*)proto)[i4] = v;
}

// ---------------- K4: split-bf16 MFMA GEMM + per-chunk argmin ----------------
// grid b*NCH2_; tile 128(T) x 64(S), BK=32. A via global_load_lds from tm_hi/lo (frag gather).
// B: fp32 load -> hi/lo convert in-kernel. 4 waves 2x2; wave tile 64(T) x 32(S).
__global__ __launch_bounds__(256) void k_gemm_argmin(
    const unsigned short* __restrict__ tm_hi, const unsigned short* __restrict__ tm_lo,
    const float* __restrict__ sup, float* __restrict__ pval, int* __restrict__ pidx){
  __shared__ __align__(16) short ldsA[16*512];   // 8 mt x 2 planes, 1KB segs
  __shared__ __align__(16) short ldsB[8*512];    // 4 nt x 2 planes
  __shared__ float normB[64];

  int b = blockIdx.x / NCH2_;
  int ch = blockIdx.x % NCH2_;
  int sbase = ch*64;
  int tid = threadIdx.x, wave = tid>>6, lane = tid&63;
  int r = tid>>2, kq = tid&3;                 // B staging: row 0..63, k-quarter
  int mbase = (wave>>1)*4;                    // 4 mt per wave
  int nbase = (wave&1)*2;                     // 2 nt per wave

  const unsigned short* asrc[4]; int adstf[4];
  #pragma unroll
  for(int ff=0; ff<4; ff++){
    int f = wave*4+ff, mt = f>>1, pl = f&1;
    const unsigned short* bp = pl ? tm_lo : tm_hi;
    asrc[ff] = bp + ((size_t)b*T_ + mt*16 + (lane&15))*D_ + (lane>>4)*8;
    adstf[ff] = f*512;
  }
  const float* pb = sup + ((size_t)b*S_ + sbase + r)*D_ + kq*8;

  f32x4 acc[4][2];
  #pragma unroll
  for(int i=0;i<4;i++)
    #pragma unroll
    for(int j=0;j<2;j++) acc[i][j] = (f32x4){0.f,0.f,0.f,0.f};
  float nrm = 0.f;
  float4 b0 = *(const float4*)pb;
  float4 b1 = *(const float4*)(pb+4);

  int seg = (r>>4)*2;
  int off = (kq*16 + (r&15))*8;

  for(int st=0; st<32; st++){
    __syncthreads();
    #pragma unroll
    for(int ff=0; ff<4; ff++)
      __builtin_amdgcn_global_load_lds(
        (const __attribute__((address_space(1))) unsigned int*)(asrc[ff] + st*32),
        (__attribute__((address_space(3))) unsigned int*)&ldsA[adstf[ff]], 16, 0, 0);
    nrm += b0.x*b0.x+b0.y*b0.y+b0.z*b0.z+b0.w*b0.w
         + b1.x*b1.x+b1.y*b1.y+b1.z*b1.z+b1.w*b1.w;
    unsigned short h0=bf16rn(b0.x),h1=bf16rn(b0.y),h2=bf16rn(b0.z),h3=bf16rn(b0.w);
    unsigned short h4=bf16rn(b1.x),h5=bf16rn(b1.y),h6=bf16rn(b1.z),h7=bf16rn(b1.w);
    unsigned short l0=bf16rn(b0.x-bf2f(h0)),l1=bf16rn(b0.y-bf2f(h1)),
                   l2=bf16rn(b0.z-bf2f(h2)),l3=bf16rn(b0.w-bf2f(h3));
    unsigned short l4=bf16rn(b1.x-bf2f(h4)),l5=bf16rn(b1.y-bf2f(h5)),
                   l6=bf16rn(b1.z-bf2f(h6)),l7=bf16rn(b1.w-bf2f(h7));
    *(uint4*)&ldsB[seg*512 + off]     = make_uint4(pack2(h0,h1),pack2(h2,h3),pack2(h4,h5),pack2(h6,h7));
    *(uint4*)&ldsB[(seg+1)*512 + off] = make_uint4(pack2(l0,l1),pack2(l2,l3),pack2(l4,l5),pack2(l6,l7));
    __syncthreads();
    if(st < 31){
      b0 = *(const float4*)(pb + (st+1)*32);
      b1 = *(const float4*)(pb + (st+1)*32 + 4);
    }
    short8 ah[4], al[4], bh[2], bl[2];
    #pragma unroll
    for(int i=0;i<4;i++){
      ah[i] = *(const short8*)&ldsA[((mbase+i)*2+0)*512 + lane*8];
      al[i] = *(const short8*)&ldsA[((mbase+i)*2+1)*512 + lane*8];
    }
    #pragma unroll
    for(int j=0;j<2;j++){
      bh[j] = *(const short8*)&ldsB[((nbase+j)*2+0)*512 + lane*8];
      bl[j] = *(const short8*)&ldsB[((nbase+j)*2+1)*512 + lane*8];
    }
    #pragma unroll
    for(int i=0;i<4;i++)
      #pragma unroll
      for(int j=0;j<2;j++){
        acc[i][j] = __builtin_amdgcn_mfma_f32_16x16x32_bf16(ah[i], bh[j], acc[i][j], 0,0,0);
        acc[i][j] = __builtin_amdgcn_mfma_f32_16x16x32_bf16(ah[i], bl[j], acc[i][j], 0,0,0);
        acc[i][j] = __builtin_amdgcn_mfma_f32_16x16x32_bf16(al[i], bh[j], acc[i][j], 0,0,0);
      }
  }

  // row norms: combine 4 k-quarters
  nrm += __shfl_xor(nrm, 1, 64);
  nrm += __shfl_xor(nrm, 2, 64);
  if(kq == 0) normB[r] = nrm;
  __syncthreads();

  // epilogue: argmin of norm[s] - 2*dot, first-min tie-break
  int q = lane >> 4, c = lane & 15;
  #pragma unroll
  for(int mt=0; mt<4; mt++){
    #pragma unroll
    for(int i=0;i<4;i++){
      int t = (wave>>1)*64 + mt*16 + q*4 + i;
      float bv = BIGF; int bi = 0x7FFFFFFF;
      #pragma unroll
      for(int nt=0; nt<2; nt++){
        int sl = (nbase+nt)*16 + c;
        float sc = normB[sl] - 2.f*acc[mt][nt][i];
        int s = sbase + sl;
        if(sc < bv || (sc == bv && s < bi)){ bv = sc; bi = s; }
      }
      #pragma unroll
      for(int o=1; o<16; o<<=1){
        float ov = __shfl_xor(bv, o, 64);
        int   oi = __shfl_xor(bi, o, 64);
        if(ov < bv || (ov == bv && oi < bi)){ bv = ov; bi = oi; }
      }
      if(c == 0){
        pval[(size_t)(b*T_ + t)*PVW_ + ch*2 + (wave&1)] = bv;
        pidx[(size_t)(b*T_ + t)*PVW_ + ch*2 + (wave&1)] = bi;
      }
    }
  }
}

// ---------------- K5: final reduce + onehot + 0.5 * tm . proto^T ----------------
__global__ __launch_bounds__(256) void k_final(
    const unsigned short* __restrict__ tm_hi, const unsigned short* __restrict__ tm_lo,
    const float* __restrict__ pval, const int* __restrict__ pidx, const int* __restrict__ labels,
    const float* __restrict__ proto, float* __restrict__ out0){
  __shared__ int lbl_t[8];
  int b = blockIdx.x >> 4, tg = blockIdx.x & 15;
  int tid = threadIdx.x;
  if(tid < 8){
    int t = tg*8 + tid;
    float bv = BIGF; int bi = 0;
    #pragma unroll
    for(int c=0;c<PVW_;c++){
      float v = pval[(size_t)(b*T_ + t)*PVW_ + c];
      if(v < bv){ bv = v; bi = pidx[(size_t)(b*T_ + t)*PVW_ + c]; }
    }
    lbl_t[tid] = labels[b*S_ + bi];
  }
  __syncthreads();
  int tl = tid >> 5, n = tid & 31;
  int t = tg*8 + tl;
  const uint2* th = (const uint2*)(tm_hi + (size_t)(b*T_+t)*D_);
  const uint2* tlo= (const uint2*)(tm_lo + (size_t)(b*T_+t)*D_);
  const float4* pr4 = (const float4*)proto + (size_t)(b*NT_+n)*(D_/4);
  float acc = 0.f;
  #pragma unroll 4
  for(int d4=0; d4<D_/4; d4++){
    uint2 h = th[d4], l = tlo[d4];
    float4 p = pr4[d4];
    float x0 = bf2f(h.x & 0xffff) + bf2f(l.x & 0xffff);
    float x1 = bf2f(h.x >> 16)    + bf2f(l.x >> 16);
    float x2 = bf2f(h.y & 0xffff) + bf2f(l.y & 0xffff);
    float x3 = bf2f(h.y >> 16)    + bf2f(l.y >> 16);
    acc += x0*p.x + x1*p.y + x2*p.z + x3*p.w;
  }
  out0[(size_t)(b*T_ + t)*NT_ + n] = 0.5f*acc + ((lbl_t[tl]==n) ? 1.f : 0.f);
}

extern "C" void kernel_launch(void* const* d_in, const int* in_sizes, int n_in,
                              void* d_out, int out_size, void* d_ws, size_t ws_size,
                              hipStream_t stream){
  const float* tr  = (const float*)d_in[0];
  const float* sup = (const float*)d_in[1];
  const float* tgt = (const float*)d_in[4];
  float* out0  = (float*)d_out;                       // (B,T,NT)
  float* proto = out0 + (size_t)B_*T_*NT_;            // (B,NT,D)

  unsigned short* tm_hi = (unsigned short*)d_ws;              // B*T*D bf16
  unsigned short* tm_lo = tm_hi + (size_t)B_*T_*D_;
  float* psums = (float*)(tm_lo + (size_t)B_*T_*D_);          // B*NT*D
  int*   pcnt  = (int*)(psums + (size_t)B_*NT_*D_);           // B*NT
  int*   labels= pcnt + (size_t)B_*NT_;                       // B*S
  float* pval  = (float*)(labels + (size_t)B_*S_);            // B*T*PVW_
  int*   pidx  = (int*)(pval + (size_t)B_*T_*PVW_);

  hipMemsetAsync(psums, 0, ((size_t)B_*NT_*D_ + B_*NT_)*sizeof(float), stream);
  k_mean<<<(B_*T_*(D_/4))/256, 256, 0, stream>>>(tr, tm_hi, tm_lo);
  k_label<<<(B_*S_)/256, 256, 0, stream>>>(tgt, labels);
  k_proto<<<B_*8, 256, 0, stream>>>(sup, labels, psums, pcnt);
  k_preduce<<<(B_*NT_*(D_/4))/256, 256, 0, stream>>>(psums, pcnt, proto);
  k_gemm_argmin<<<B_*NCH2_, 256, 0, stream>>>(tm_hi, tm_lo, sup, pval, pidx);
  k_final<<<B_*16, 256, 0, stream>>>(tm_hi, tm_lo, pval, pidx, labels, proto, out0);
}